// Round 11
// baseline (312.503 us; speedup 1.0000x reference)
//
#include <hip/hip_runtime.h>
#include <hip/hip_bf16.h>
#include <hip/hip_fp16.h>
#include <math.h>

// ---------------------------------------------------------------------------
// DisplacementTensors: rad = MLP(radial_encode(|r|)) depends only on |r| ->
// tabulate [F(d) | F(d)@w_v | F(d)@w_d] (96 f32/row, 8192 nearest-neighbor
// entries, 3 MB, L2-resident).
// R11: collapse the launch-overhead-dominated aux pipeline:
//   k_table : self-contained (stages weights into LDS, writes dtype flag)
//   k_csr   : ONE kernel = hist -> colscan -> rowstart-scan -> place, with
//             manual grid barriers (256 co-resident blocks, atomic spin)
//   k_nodes2: two nodes/wave, x4-unrolled latency-filling main loop
// Payload: float4 (rs0,rs1,rs2, table BYTE offset) when ws allows, else
// packed uint2 (f16 rs | u16 idx).  dtype (bf16/f32) runtime-detected.
// ---------------------------------------------------------------------------

#define TSIZE 8192
#define DMAX  2.0f           // RBF centers <=1, width 1/8 -> F const beyond ~2
#define EPB   4              // entries per block in k_table
#define HB    128            // edge chunks
#define TILE  10240          // node-tile size (40 KB LDS)
#define NPB   4              // waves per block in k_nodes2 (8 nodes/block)

// LDS weight offsets (floats)
#define O_WRAD 0
#define O_BRAD 256
#define O_WDIR 288
#define O_W1   1312
#define O_B1   3360
#define O_W2   3424
#define O_B2   7520
#define O_W3   7584
#define O_B3   9632
#define O_WV   9664
#define O_WD   10688
#define W_TOT  11712

__device__ __forceinline__ float lrelu(float x) { return x > 0.0f ? x : 0.1f * x; }

__device__ __forceinline__ float ldf(const void* p, int i, bool f32) {
    return f32 ? ((const float*)p)[i]
               : __uint_as_float(((unsigned int)((const unsigned short*)p)[i]) << 16);
}
__device__ __forceinline__ void stf(void* p, size_t i, float v, bool f32) {
    if (f32) ((float*)p)[i] = v;
    else     ((__hip_bfloat16*)p)[i] = __float2bfloat16(v);
}

// probe first 128 halfwords of r_ij as bf16: f32 data's low halves have random
// exponents -> non-finite/huge values appear with P ~ 1-1e-16.
__device__ __forceinline__ bool detect_f32(const void* r) {
    const unsigned short* p = (const unsigned short*)r;
    int bad = 0;
#pragma unroll 8
    for (int i = 0; i < 128; i++) {
        float v = __uint_as_float(((unsigned int)p[i]) << 16);
        bad |= (!isfinite(v) || fabsf(v) > 1e5f) ? 1 : 0;
    }
    return bad != 0;
}

// --- LUT build: self-contained (stages weights into LDS, writes flag) -----
__device__ __forceinline__ void load_seg(float* dst, const void* src, int cnt,
                                         bool f32, int tid, int bs) {
    for (int i = tid; i < cnt; i += bs) dst[i] = ldf(src, i, f32);
}

__global__ void __launch_bounds__(64 * EPB) k_table(
        const void* __restrict__ r_ij,
        const void* w_rad, const void* b_rad, const void* w_direct,
        const void* w1, const void* b1, const void* w2, const void* b2,
        const void* w3, const void* b3, const void* w_v, const void* w_d,
        int* __restrict__ flag, float* __restrict__ tabI) {
    __shared__ float W[W_TOT];
    __shared__ float Lh[EPB][32], Lt1[EPB][64], Lt2[EPB][64], Lrad[EPB][32];

    const bool f32 = detect_f32(r_ij);
    if (blockIdx.x == 0 && threadIdx.x == 0) flag[0] = f32 ? 1 : 0;

    const int tid = threadIdx.x;
    const int bs = 64 * EPB;
    load_seg(W + O_WRAD, w_rad,    256,  f32, tid, bs);
    load_seg(W + O_BRAD, b_rad,    32,   f32, tid, bs);
    load_seg(W + O_WDIR, w_direct, 1024, f32, tid, bs);
    load_seg(W + O_W1,   w1,       2048, f32, tid, bs);
    load_seg(W + O_B1,   b1,       64,   f32, tid, bs);
    load_seg(W + O_W2,   w2,       4096, f32, tid, bs);
    load_seg(W + O_B2,   b2,       64,   f32, tid, bs);
    load_seg(W + O_W3,   w3,       2048, f32, tid, bs);
    load_seg(W + O_B3,   b3,       32,   f32, tid, bs);
    load_seg(W + O_WV,   w_v,      1024, f32, tid, bs);
    load_seg(W + O_WD,   w_d,      1024, f32, tid, bs);
    __syncthreads();

    const int s = threadIdx.x >> 6;          // entry slot (wave)
    const int j = threadIdx.x & 63;          // neuron
    const int e = blockIdx.x * EPB + s;
    const float d = (float)e * (DMAX / (float)(TSIZE - 1));

    float enc[8];
#pragma unroll
    for (int k = 0; k < 8; k++) {
        float t = (d - (float)k * (1.0f / 7.0f)) * 8.0f;
        enc[k] = expf(-t * t);
    }

    if (j < 32) {
        float hv = W[O_BRAD + j];
#pragma unroll
        for (int k = 0; k < 8; k++) hv = fmaf(enc[k], W[O_WRAD + k * 32 + j], hv);
        Lh[s][j] = hv;
    }
    __syncthreads();

    {
        float v = W[O_B1 + j];
#pragma unroll
        for (int i = 0; i < 32; i++) v = fmaf(Lh[s][i], W[O_W1 + i * 64 + j], v);
        Lt1[s][j] = lrelu(v);
    }
    __syncthreads();

    {
        float v = W[O_B2 + j];
#pragma unroll
        for (int i = 0; i < 64; i++) v = fmaf(Lt1[s][i], W[O_W2 + i * 64 + j], v);
        Lt2[s][j] = lrelu(v);
    }
    __syncthreads();

    if (j < 32) {
        float v = W[O_B3 + j];
#pragma unroll
        for (int i = 0; i < 64; i++) v = fmaf(Lt2[s][i], W[O_W3 + i * 32 + j], v);
#pragma unroll
        for (int i = 0; i < 32; i++) v = fmaf(Lh[s][i], W[O_WDIR + i * 32 + j], v);
        Lrad[s][j] = v;
        tabI[e * 96 + j] = v;
    }
    __syncthreads();

    if (j < 32) {
        float sv = 0.0f, sd = 0.0f;
#pragma unroll
        for (int i = 0; i < 32; i++) {
            float ri = Lrad[s][i];
            sv = fmaf(ri, W[O_WV + i * 32 + j], sv);
            sd = fmaf(ri, W[O_WD + i * 32 + j], sd);
        }
        tabI[e * 96 + 32 + j] = sv;
        tabI[e * 96 + 64 + j] = sd;
    }
}

// --- grid barrier (all blocks co-resident; bar slots zeroed by memset) -----
__device__ __forceinline__ void gbar(int* bar, int slot, int nb) {
    __syncthreads();
    if (threadIdx.x == 0) {
        __threadfence();
        atomicAdd(&bar[slot], 1);
        while (atomicAdd(&bar[slot], 0) < nb) { }
    }
    __syncthreads();
    __threadfence();
}

// --- fused CSR build + payload placement (hist/colscan/scan/place) ---------
// grid: HB * ntiles blocks of 256; requires all blocks co-resident (256
// blocks, 40 KB LDS -> 4/CU possible) and gridDim*256 >= N.
template <bool P16>
__global__ void __launch_bounds__(256) k_csr(
        const int* __restrict__ src, int E, int chunk,
        const void* __restrict__ r_ij, const int* __restrict__ flag,
        unsigned short* __restrict__ cnt, int* __restrict__ tot,
        int* __restrict__ coarse, int* __restrict__ rowstart,
        int* __restrict__ bar, void* __restrict__ epsv, int N) {
    __shared__ int lbuf[TILE];
    const int nb = gridDim.x;
    const int b = blockIdx.x % HB;           // edge chunk
    const int t = blockIdx.x / HB;           // node tile
    const int lo = b * chunk;
    const int hi = min(lo + chunk, E);
    const int t0 = t * TILE;
    const int tl = min(TILE, N - t0);

    // ---- phase 1: LDS histogram for (chunk b, tile t) ----
    for (int i = threadIdx.x; i < tl; i += 256) lbuf[i] = 0;
    __syncthreads();
    for (int e = lo + threadIdx.x; e < hi; e += 256) {
        const int s = src[e] - t0;
        if ((unsigned)s < (unsigned)tl) atomicAdd(&lbuf[s], 1);
    }
    __syncthreads();
    {
        unsigned short* out = cnt + (size_t)(t * HB + b) * TILE;
        for (int i = threadIdx.x; i < tl; i += 256)
            out[i] = (unsigned short)lbuf[i];
    }
    gbar(bar, 0, nb);

    // ---- phase 2: per-node column scan over chunks + per-wave coarse ----
    {
        const int gtid = blockIdx.x * 256 + threadIdx.x;
        const int lane = threadIdx.x & 63;
        const int w = gtid >> 6;
        int run = 0;
        if (gtid < N) {
            const int tt = gtid / TILE;
            const int nl = gtid % TILE;
            unsigned short* col = cnt + (size_t)(tt * HB) * TILE + nl;
#pragma unroll 4
            for (int c = 0; c < HB; c++) {
                int v = col[(size_t)c * TILE];
                col[(size_t)c * TILE] = (unsigned short)run;
                run += v;
            }
            tot[gtid] = run;
        }
        int sum = run;
        for (int off = 32; off > 0; off >>= 1) sum += __shfl_down(sum, off);
        if (lane == 0) coarse[w] = sum;
    }
    gbar(bar, 1, nb);

    // ---- phase 3: rowstart = global exclusive prefix of tot ----
    {
        const int gtid = blockIdx.x * 256 + threadIdx.x;
        const int lane = threadIdx.x & 63;
        const int w = gtid >> 6;
        int cp = 0;
        for (int j = lane; j < w; j += 64) cp += coarse[j];
        for (int off = 32; off > 0; off >>= 1) cp += __shfl_down(cp, off);
        const int cpre = __shfl(cp, 0);
        const int v = (gtid < N) ? tot[gtid] : 0;
        int inc = v;
        for (int off = 1; off < 64; off <<= 1) {
            int y = __shfl_up(inc, off);
            if (lane >= off) inc += y;
        }
        if (gtid < N) rowstart[gtid] = cpre + inc - v;
        if (gtid == N - 1) rowstart[N] = cpre + inc;
    }
    gbar(bar, 2, nb);

    // ---- phase 4: place payload via LDS cursor ----
    {
        const bool f32 = flag[0] != 0;
        const unsigned short* base = cnt + (size_t)(t * HB + b) * TILE;
        for (int i = threadIdx.x; i < tl; i += 256)
            lbuf[i] = rowstart[t0 + i] + (int)base[i];
        __syncthreads();
        for (int e = lo + threadIdx.x; e < hi; e += 256) {
            const int s = src[e] - t0;
            if ((unsigned)s < (unsigned)tl) {
                const int pos = atomicAdd(&lbuf[s], 1);
                const float x = ldf(r_ij, 3 * e + 0, f32);
                const float y = ldf(r_ij, 3 * e + 1, f32);
                const float z = ldf(r_ij, 3 * e + 2, f32);
                const float d2 = x * x + y * y + z * z;
                const float inv = rsqrtf(1.0f + 49.0f * d2);  // tens_sigmoid(7r)
                const float u = fminf(sqrtf(d2), DMAX) * ((float)(TSIZE - 1) / DMAX);
                const int ti = (int)(u + 0.5f);               // nearest
                const float rs0 = 7.0f * x * inv, rs1 = 7.0f * y * inv,
                            rs2 = 7.0f * z * inv;
                if (P16) {
                    ((float4*)epsv)[pos] =
                        make_float4(rs0, rs1, rs2, __int_as_float(ti * 384));
                } else {
                    const unsigned int h0 = __half_as_ushort(__float2half(rs0));
                    const unsigned int h1 = __half_as_ushort(__float2half(rs1));
                    const unsigned int h2 = __half_as_ushort(__float2half(rs2));
                    ((uint2*)epsv)[pos] =
                        make_uint2(h0 | (h1 << 16), h2 | ((unsigned)ti << 16));
                }
            }
        }
    }
}

// --- per-node accumulation: TWO nodes per wave, x4 unroll ------------------
template <bool P16>
__global__ void __launch_bounds__(64 * NPB) k_nodes2(
    const void* __restrict__ epsv,
    const int* __restrict__ rowstart,
    const float* __restrict__ tabI,
    const int* __restrict__ flag,
    void* __restrict__ out, int N) {
    const int wave = threadIdx.x >> 6;
    const int lane = threadIdx.x & 63;
    const int n0 = (blockIdx.x * NPB + wave) * 2;
    const int a = lane & 31;
    const int half = lane >> 5;
    const int myn = n0 + half;
    const bool f32 = flag[0] != 0;
    const char* tabA = (const char*)tabI + (a << 2);

    int s0 = 0, s1 = 0;
    if (myn < N) { s0 = rowstart[myn]; s1 = rowstart[myn + 1]; }
    const int mylen = s1 - s0;
    const int lenA = __shfl(mylen, 0);
    const int lenB = __shfl(mylen, 32);
    const int minl = min(lenA, lenB);
    const int maxl = max(lenA, lenB);

    float accA = 0.f, v0 = 0.f, v1 = 0.f, v2 = 0.f;
    float d00 = 0.f, d01 = 0.f, d02 = 0.f,
          d10 = 0.f, d11 = 0.f, d12 = 0.f,
          d20 = 0.f, d21 = 0.f, d22 = 0.f;

#define EDGE_LOAD(K, IDX)                                                     \
    do {                                                                      \
        if (P16) {                                                            \
            const float4 q = ((const float4*)epsv)[IDX];                      \
            xs[K] = q.x; ys[K] = q.y; zs[K] = q.z;                            \
            ps[K] = (const float*)(tabA + __float_as_int(q.w));               \
        } else {                                                              \
            const uint2 q = ((const uint2*)epsv)[IDX];                        \
            xs[K] = __half2float(__ushort_as_half((unsigned short)(q.x & 0xffff))); \
            ys[K] = __half2float(__ushort_as_half((unsigned short)(q.x >> 16)));    \
            zs[K] = __half2float(__ushort_as_half((unsigned short)(q.y & 0xffff))); \
            ps[K] = (const float*)(tabA + (int)(q.y >> 16) * 384);            \
        }                                                                     \
    } while (0)

#define EDGE_ACC(X, Y, Z, P)                                                  \
    do {                                                                      \
        const float ra = (P)[0], rv = (P)[32], rd = (P)[64];                  \
        accA += ra;                                                           \
        v0 += rv * (X); v1 += rv * (Y); v2 += rv * (Z);                       \
        const float t0 = rd * (X), t1 = rd * (Y), t2 = rd * (Z);              \
        d00 += t0 * (X); d01 += t0 * (Y); d02 += t0 * (Z);                    \
        d10 += t1 * (X); d11 += t1 * (Y); d12 += t1 * (Z);                    \
        d20 += t2 * (X); d21 += t2 * (Y); d22 += t2 * (Z);                    \
    } while (0)

    int i = 0;
    for (; i + 3 < minl; i += 4) {            // x4 unroll, no predication
        float xs[4], ys[4], zs[4];
        const float* ps[4];
        EDGE_LOAD(0, s0 + i + 0);
        EDGE_LOAD(1, s0 + i + 1);
        EDGE_LOAD(2, s0 + i + 2);
        EDGE_LOAD(3, s0 + i + 3);
#pragma unroll
        for (int k = 0; k < 4; k++) EDGE_ACC(xs[k], ys[k], zs[k], ps[k]);
    }
    for (; i < maxl; i++) {                   // remainder + divergent tail
        if (i < mylen) {
            float xs[1], ys[1], zs[1];
            const float* ps[1];
            EDGE_LOAD(0, s0 + i);
            EDGE_ACC(xs[0], ys[0], zs[0], ps[0]);
        }
    }
#undef EDGE_LOAD
#undef EDGE_ACC

    if (myn >= N) return;
    const size_t baseV = (size_t)N * 32;
    const size_t baseD = (size_t)N * 128;
    stf(out, (size_t)myn * 32 + a, accA, f32);
    const size_t vb = baseV + (size_t)myn * 96 + a * 3;
    stf(out, vb + 0, v0, f32);
    stf(out, vb + 1, v1, f32);
    stf(out, vb + 2, v2, f32);
    const size_t db = baseD + (size_t)myn * 288 + a * 9;
    stf(out, db + 0, d00, f32);
    stf(out, db + 1, d01, f32);
    stf(out, db + 2, d02, f32);
    stf(out, db + 3, d10, f32);
    stf(out, db + 4, d11, f32);
    stf(out, db + 5, d12, f32);
    stf(out, db + 6, d20, f32);
    stf(out, db + 7, d21, f32);
    stf(out, db + 8, d22, f32);
}

// --- fallback CSR (global atomics) + perm-based nodes ----------------------
__global__ void k_rank_g(const int* __restrict__ src, int* __restrict__ counts,
                         int* __restrict__ rank, int E) {
    int e = blockIdx.x * blockDim.x + threadIdx.x;
    if (e < E) rank[e] = atomicAdd(&counts[src[e]], 1);
}
__global__ void k_scan_g(const int* __restrict__ counts, int* __restrict__ rowstart,
                         int N, int E) {
    __shared__ int part[1024];
    const int t = threadIdx.x;
    const int CH = (N + 1023) / 1024;
    const int lo = t * CH;
    const int hi = min(lo + CH, N);
    int s = 0;
    for (int i = lo; i < hi; i++) s += counts[i];
    part[t] = s;
    __syncthreads();
    for (int off = 1; off < 1024; off <<= 1) {
        int v = part[t];
        int w = (t >= off) ? part[t - off] : 0;
        __syncthreads();
        part[t] = v + w;
        __syncthreads();
    }
    int run = (t == 0) ? 0 : part[t - 1];
    for (int i = lo; i < hi; i++) { rowstart[i] = run; run += counts[i]; }
    if (t == 0) rowstart[N] = E;
}
__global__ void k_place_g(const int* __restrict__ src, const int* __restrict__ rank,
                          const int* __restrict__ rowstart,
                          int* __restrict__ perm, int E) {
    int e = blockIdx.x * blockDim.x + threadIdx.x;
    if (e < E) perm[rowstart[src[e]] + rank[e]] = e;
}
__global__ void __launch_bounds__(256) k_nodes_fb(
    const int* __restrict__ perm, const void* __restrict__ r_ij,
    const int* __restrict__ rowstart, const float* __restrict__ tabI,
    const int* __restrict__ flag, void* __restrict__ out, int N) {
    const int wave = threadIdx.x >> 6;
    const int lane = threadIdx.x & 63;
    const int n = blockIdx.x * 4 + wave;
    if (n >= N) return;
    const int a = lane & 31;
    const bool hi = (lane >> 5) != 0;
    const bool f32 = flag[0] != 0;
    const int s0 = rowstart[n], s1 = rowstart[n + 1];
    float accR = 0.f, acc1 = 0.f, acc2 = 0.f, acc3 = 0.f,
          acc4 = 0.f, acc5 = 0.f, acc6 = 0.f;
    for (int idx = s0; idx < s1; idx++) {
        const int e = perm[idx];
        const float x0 = ldf(r_ij, 3 * e + 0, f32);
        const float y0 = ldf(r_ij, 3 * e + 1, f32);
        const float z0 = ldf(r_ij, 3 * e + 2, f32);
        const float d2 = x0 * x0 + y0 * y0 + z0 * z0;
        const float inv = rsqrtf(1.0f + 49.0f * d2);
        const float x = 7.0f * x0 * inv, y = 7.0f * y0 * inv, z = 7.0f * z0 * inv;
        const float u = fminf(sqrtf(d2), DMAX) * ((float)(TSIZE - 1) / DMAX);
        const int b = (int)(u + 0.5f) * 96 + a;
        const float ra = tabI[b], rv = tabI[b + 32], rd = tabI[b + 64];
        const float b1 = (hi ? rd : rv) * (hi ? y : 1.0f);
        const float b2 = rd * (hi ? z : x);
        accR += ra;
        acc1 += b1 * x; acc2 += b1 * y; acc3 += b1 * z;
        acc4 += b2 * x; acc5 += b2 * y; acc6 += b2 * z;
    }
    const size_t baseV = (size_t)N * 32;
    const size_t baseD = (size_t)N * 128;
    if (!hi) {
        stf(out, (size_t)n * 32 + a, accR, f32);
        const size_t vb = baseV + (size_t)n * 96 + a * 3;
        stf(out, vb + 0, acc1, f32);
        stf(out, vb + 1, acc2, f32);
        stf(out, vb + 2, acc3, f32);
        const size_t db = baseD + (size_t)n * 288 + a * 9;
        stf(out, db + 0, acc4, f32);
        stf(out, db + 1, acc5, f32);
        stf(out, db + 2, acc6, f32);
    } else {
        const size_t db = baseD + (size_t)n * 288 + a * 9;
        stf(out, db + 3, acc1, f32);
        stf(out, db + 4, acc2, f32);
        stf(out, db + 5, acc3, f32);
        stf(out, db + 6, acc4, f32);
        stf(out, db + 7, acc5, f32);
        stf(out, db + 8, acc6, f32);
    }
}

extern "C" void kernel_launch(void* const* d_in, const int* in_sizes, int n_in,
                              void* d_out, int out_size, void* d_ws, size_t ws_size,
                              hipStream_t stream) {
    const void* r_ij     = d_in[0];
    const void* w_rad    = d_in[1];
    const void* b_rad    = d_in[2];
    const void* w_direct = d_in[3];
    const void* w1       = d_in[4];
    const void* b1       = d_in[5];
    const void* w2       = d_in[6];
    const void* b2       = d_in[7];
    const void* w3       = d_in[8];
    const void* b3       = d_in[9];
    const void* w_v      = d_in[10];
    const void* w_d      = d_in[11];
    const int* edges_src = (const int*)d_in[12];

    const int E = in_sizes[12];
    const int N = out_size / 416;   // 32 + 96 + 288 per node
    const int chunk = (E + HB - 1) / HB;
    const int ntiles = (N + TILE - 1) / TILE;
    const int nblocks = HB * ntiles;

    // fast path layout: eps | flag(4)+bar(16) | tabI | cnt u16 | tot | coarse | rowstart
    const size_t cntBytes  = (size_t)ntiles * HB * TILE * 2;
    const size_t tailBytes = 20 * 4 + (size_t)TSIZE * 96 * 4 + cntBytes
                           + ((size_t)N + 1024 + N + 1) * 4;
    const bool sizeOK = (N <= nblocks * 256) && (ntiles <= 8);
    const bool p16 = sizeOK && ws_size >= (size_t)E * 16 + tailBytes + 64;
    const bool p8  = sizeOK && !p16 && ws_size >= (size_t)E * 8 + tailBytes + 64;

    char* w = (char*)d_ws;
    if (p16 || p8) {
        const size_t slot = (size_t)E * (p16 ? 16 : 8);
        void* eps     = (void*)w;
        int* flag     = (int*)(w + slot);
        int* bar      = flag + 4;             // 16 ints
        float* tabI   = (float*)(bar + 16);
        unsigned short* cnt = (unsigned short*)(tabI + (size_t)TSIZE * 96);
        int* tot      = (int*)((char*)cnt + cntBytes);
        int* coarse   = tot + N;              // 1024
        int* rowstart = coarse + 1024;        // N+1

        hipMemsetAsync(bar, 0, 16 * 4, stream);
        k_table<<<TSIZE / EPB, 64 * EPB, 0, stream>>>(
            r_ij, w_rad, b_rad, w_direct, w1, b1, w2, b2, w3, b3, w_v, w_d,
            flag, tabI);
        const int nodeBlocks = (N + 2 * NPB - 1) / (2 * NPB);
        if (p16) {
            k_csr<true><<<nblocks, 256, 0, stream>>>(
                edges_src, E, chunk, r_ij, flag, cnt, tot, coarse, rowstart,
                bar, eps, N);
            k_nodes2<true><<<nodeBlocks, 64 * NPB, 0, stream>>>(
                eps, rowstart, tabI, flag, d_out, N);
        } else {
            k_csr<false><<<nblocks, 256, 0, stream>>>(
                edges_src, E, chunk, r_ij, flag, cnt, tot, coarse, rowstart,
                bar, eps, N);
            k_nodes2<false><<<nodeBlocks, 64 * NPB, 0, stream>>>(
                eps, rowstart, tabI, flag, d_out, N);
        }
    } else {
        // fallback: global-atomic rank path, perm-indexed nodes
        int* perm     = (int*)w;              // E
        int* flag     = (int*)(w + (size_t)E * 4);
        float* tabI   = (float*)(flag + 4);
        int* counts   = (int*)(tabI + (size_t)TSIZE * 96);
        int* rowstart = counts + N;           // N+1
        int* rank     = rowstart + N + 1;     // E

        hipMemsetAsync(counts, 0, (size_t)N * 4, stream);
        k_table<<<TSIZE / EPB, 64 * EPB, 0, stream>>>(
            r_ij, w_rad, b_rad, w_direct, w1, b1, w2, b2, w3, b3, w_v, w_d,
            flag, tabI);
        k_rank_g<<<(E + 255) / 256, 256, 0, stream>>>(edges_src, counts, rank, E);
        k_scan_g<<<1, 1024, 0, stream>>>(counts, rowstart, N, E);
        k_place_g<<<(E + 255) / 256, 256, 0, stream>>>(edges_src, rank, rowstart,
                                                       perm, E);
        k_nodes_fb<<<(N + 3) / 4, 256, 0, stream>>>(
            perm, r_ij, rowstart, tabI, flag, d_out, N);
    }
}